// Round 3
// baseline (951.606 us; speedup 1.0000x reference)
//
#include <hip/hip_runtime.h>
#include <hip/hip_bf16.h>

// Problem constants
#define BB   16
#define LL   50
#define PP   49
#define TT   20
#define DD   512
#define HH   8
#define DHH  64
#define DFF  2048

#define BL     (BB*LL)          // 800
#define ROWS_I (BL*TT)          // 16000
#define ROWS_T (BL*PP)          // 39200
#define ROWS_A (ROWS_I+ROWS_T)  // 55200
#define OUT_I_ELEMS ((size_t)ROWS_I*DD)   // 8,192,000 (elements)
#define CHUNK 19600             // tit branch processed in 2 chunks

// ws layout (bytes) — total 165,789,696 (< proven 240 MB)
//  R0 act/hid : [0, 80,281,600)     hid bf16 (55200x512, early) / act bf16 (<=19600x2048)
//  R1 out_bf  : [80,281,600, +56,524,800)   proj output bf16
//  R2 f2 bf16 : [136,806,400, +20,070,400)  ffn2 output bf16 (per chunk)
//  R3 weights : [156,876,800, +8,912,896)
#define R1_OFF 80281600ull
#define R2_OFF 136806400ull
#define R3_OFF 156876800ull

typedef __attribute__((ext_vector_type(8))) short bf16x8;
typedef __attribute__((ext_vector_type(8))) unsigned short ushort8;
typedef __attribute__((ext_vector_type(4))) float f32x4;

__device__ __forceinline__ float bf2f(unsigned short u) {
    union { unsigned int i; float f; } w; w.i = ((unsigned int)u) << 16; return w.f;
}
__device__ __forceinline__ unsigned short f2bf(float f) {
    union { float f; unsigned int i; } w; w.f = f;
    unsigned int x = w.i;
    unsigned int r = (x + 0x7fffu + ((x >> 16) & 1u)) >> 16;
    return (unsigned short)r;
}
__device__ __forceinline__ float gelu_tanh_f(float x) {
    float c = 0.7978845608028654f * (x + 0.044715f * x * x * x);
    return 0.5f * x * (1.0f + tanhf(c));
}

// ---------------------------------------------------------------------------
// fp32 -> bf16 convert (n4 = n/4)
// ---------------------------------------------------------------------------
__global__ __launch_bounds__(256) void cvt_kernel(
    const float* __restrict__ s, unsigned short* __restrict__ d, int n4)
{
    int i = blockIdx.x * 256 + threadIdx.x;
    if (i < n4) {
        float4 v = ((const float4*)s)[i];
        ushort4 u;
        u.x = f2bf(v.x); u.y = f2bf(v.y); u.z = f2bf(v.z); u.w = f2bf(v.w);
        ((ushort4*)d)[i] = u;
    }
}

// ---------------------------------------------------------------------------
// MFMA attention: one block per (bl, h), 4 waves.
//   S = imgh @ tith^T / 8  (MFMA, M=64 N=32 K=64)
//   softmax (masked, per-head scales) -> pI bf16 [p][t], pT bf16 [t][p]
//   hid_img = pT @ imgT (M=32 N=64 K=64), hid_tit = pI @ titT (M=64 N=64 K=32)
// Writes hid bf16: img rows [0,16000), tit rows [16000,55200).
// ---------------------------------------------------------------------------
__global__ __launch_bounds__(256) void attn_kernel(
    const float* __restrict__ img, const float* __restrict__ title,
    const int* __restrict__ mask, const float* __restrict__ scale_img,
    const float* __restrict__ scale_tit, unsigned short* __restrict__ hid)
{
    const int blh = blockIdx.x;
    const int h  = blh & 7;
    const int bl = blh >> 3;
    const int tid = threadIdx.x;
    const int w    = tid >> 6;     // wave 0..3
    const int lane = tid & 63;
    const int lane_m = lane & 15;
    const int lane_q = lane >> 4;  // 0..3

    __shared__ __align__(16) unsigned short s_img [64][72];  // [p][d]
    __shared__ __align__(16) unsigned short s_tit [32][72];  // [t][d]
    __shared__ __align__(16) unsigned short s_imgT[64][72];  // [d][p]
    __shared__ __align__(16) unsigned short s_titT[64][40];  // [d][t]
    __shared__ __align__(16) float          s_S   [64][36];  // [p][t]
    __shared__ __align__(16) unsigned short s_pI  [64][40];  // [p][t]
    __shared__ __align__(16) unsigned short s_pT  [32][72];  // [t][p]
    __shared__ int msk[TT];

    const float* imgbase = img   + (size_t)bl * PP * DD + h * DHH;
    const float* titbase = title + (size_t)bl * TT * DD + h * DHH;

    // P0: stage (zero-padded) bf16 tiles
    for (int i = tid; i < 64 * 64; i += 256) {
        int p = i >> 6, d = i & 63;
        s_img[p][d] = (p < PP) ? f2bf(imgbase[(size_t)p * DD + d]) : (unsigned short)0;
    }
    for (int i = tid; i < 32 * 64; i += 256) {
        int t = i >> 6, d = i & 63;
        s_tit[t][d] = (t < TT) ? f2bf(titbase[(size_t)t * DD + d]) : (unsigned short)0;
    }
    if (tid < TT) msk[tid] = mask[bl * TT + tid];
    __syncthreads();

    // P1: transposes + S via MFMA
    for (int i = tid; i < 64 * 64; i += 256) {
        int p = i >> 6, d = i & 63;
        s_imgT[d][p] = s_img[p][d];
    }
    for (int i = tid; i < 32 * 64; i += 256) {
        int t = i >> 6, d = i & 63;
        s_titT[d][t] = s_tit[t][d];
    }
    {
        f32x4 accS[2] = {};
        #pragma unroll
        for (int kk = 0; kk < 2; ++kk) {
            const int kb = kk * 32 + lane_q * 8;
            bf16x8 af = *(const bf16x8*)&s_img[w * 16 + lane_m][kb];
            #pragma unroll
            for (int nt = 0; nt < 2; ++nt) {
                bf16x8 bfv = *(const bf16x8*)&s_tit[nt * 16 + lane_m][kb];
                accS[nt] = __builtin_amdgcn_mfma_f32_16x16x32_bf16(af, bfv, accS[nt], 0, 0, 0);
            }
        }
        #pragma unroll
        for (int nt = 0; nt < 2; ++nt)
            #pragma unroll
            for (int r = 0; r < 4; ++r)
                s_S[w * 16 + lane_q * 4 + r][nt * 16 + lane_m] = accS[nt][r] * 0.125f;
    }
    __syncthreads();

    // P2: softmaxes -> bf16 P matrices (zero-padded)
    if (tid < 64) {
        const int p = tid;
        if (p < PP) {
            const float sc = scale_img[h * PP + p];
            float m = -1e30f;
            #pragma unroll
            for (int t = 0; t < TT; ++t) {
                float x = (msk[t] == 0) ? -1e9f : s_S[p][t] * sc;
                m = fmaxf(m, x);
            }
            float e[TT]; float sum = 0.f;
            #pragma unroll
            for (int t = 0; t < TT; ++t) {
                float x = (msk[t] == 0) ? -1e9f : s_S[p][t] * sc;
                e[t] = __expf(x - m); sum += e[t];
            }
            float inv = 1.f / sum;
            #pragma unroll
            for (int t = 0; t < TT; ++t) s_pI[p][t] = f2bf(e[t] * inv);
            for (int t = TT; t < 32; ++t) s_pI[p][t] = 0;
        } else {
            for (int t = 0; t < 32; ++t) s_pI[p][t] = 0;
        }
    } else if (tid < 96) {
        const int t = tid - 64;
        if (t < TT) {
            const float sc = scale_tit[h * TT + t];
            const bool dead = (msk[t] == 0);
            float m = -1e30f;
            for (int p = 0; p < PP; ++p) {
                float x = dead ? -1e9f : s_S[p][t] * sc;
                m = fmaxf(m, x);
            }
            float sum = 0.f;
            for (int p = 0; p < PP; ++p) {
                float x = dead ? -1e9f : s_S[p][t] * sc;
                sum += __expf(x - m);
            }
            float inv = 1.f / sum;
            for (int p = 0; p < PP; ++p) {
                float x = dead ? -1e9f : s_S[p][t] * sc;
                s_pT[t][p] = f2bf(__expf(x - m) * inv);
            }
            for (int p = PP; p < 64; ++p) s_pT[t][p] = 0;
        } else {
            for (int p = 0; p < 64; ++p) s_pT[t][p] = 0;
        }
    }
    __syncthreads();

    // P3: PV1 (hid_img) and PV2 (hid_tit); wave w owns d-tile w
    {
        f32x4 acc[2] = {};
        #pragma unroll
        for (int kk = 0; kk < 2; ++kk) {
            const int kb = kk * 32 + lane_q * 8;
            bf16x8 bfv = *(const bf16x8*)&s_imgT[w * 16 + lane_m][kb];
            #pragma unroll
            for (int mt = 0; mt < 2; ++mt) {
                bf16x8 af = *(const bf16x8*)&s_pT[mt * 16 + lane_m][kb];
                acc[mt] = __builtin_amdgcn_mfma_f32_16x16x32_bf16(af, bfv, acc[mt], 0, 0, 0);
            }
        }
        #pragma unroll
        for (int mt = 0; mt < 2; ++mt)
            #pragma unroll
            for (int r = 0; r < 4; ++r) {
                const int t = mt * 16 + lane_q * 4 + r;
                if (t < TT)
                    hid[(size_t)(bl * TT + t) * DD + h * DHH + w * 16 + lane_m] = f2bf(acc[mt][r]);
            }
    }
    {
        f32x4 acc[4] = {};
        const int kb = lane_q * 8;
        bf16x8 bfv = *(const bf16x8*)&s_titT[w * 16 + lane_m][kb];
        #pragma unroll
        for (int mt = 0; mt < 4; ++mt) {
            bf16x8 af = *(const bf16x8*)&s_pI[mt * 16 + lane_m][kb];
            acc[mt] = __builtin_amdgcn_mfma_f32_16x16x32_bf16(af, bfv, acc[mt], 0, 0, 0);
        }
        #pragma unroll
        for (int mt = 0; mt < 4; ++mt)
            #pragma unroll
            for (int r = 0; r < 4; ++r) {
                const int p = mt * 16 + lane_q * 4 + r;
                if (p < PP)
                    hid[OUT_I_ELEMS + (size_t)(bl * PP + p) * DD + h * DHH + w * 16 + lane_m] = f2bf(acc[mt][r]);
            }
    }
}

// ---------------------------------------------------------------------------
// MFMA GEMM: C[M,N](bf16) = A[M,K](bf16) @ Bw[N,K](bf16)^T + bias[N], opt GELU
// 128x128 tile, BK=32, 4 waves, mfma_f32_16x16x32_bf16, global_load_lds w=16.
// ---------------------------------------------------------------------------
template<bool GELU>
__global__ __launch_bounds__(256) void gemm_mfma(
    const unsigned short* __restrict__ A, const unsigned short* __restrict__ Bw,
    const float* __restrict__ bias, unsigned short* __restrict__ C,
    int M, int N, int K)
{
    __shared__ unsigned short As[128 * 32];
    __shared__ unsigned short Bs[128 * 32];
    const int tid  = threadIdx.x;
    const int wave = tid >> 6;
    const int lane = tid & 63;
    const int row0 = blockIdx.y * 128;
    const int col0 = blockIdx.x * 128;
    const int m_off = (wave >> 1) * 64;
    const int n_off = (wave & 1) * 64;
    const int lane_m = lane & 15;
    const int lane_k = (lane >> 4) * 8;

    f32x4 acc[4][4] = {};

    for (int k0 = 0; k0 < K; k0 += 32) {
        #pragma unroll
        for (int q = 0; q < 2; ++q) {
            const int li = q * 256 + tid;
            int gr = row0 + (li >> 2);
            if (gr >= M) gr = M - 1;
            const unsigned short* gp = A + (size_t)gr * K + k0 + (li & 3) * 8;
            __builtin_amdgcn_global_load_lds(
                (const __attribute__((address_space(1))) unsigned int*)gp,
                (__attribute__((address_space(3))) unsigned int*)&As[li * 8], 16, 0, 0);
        }
        #pragma unroll
        for (int q = 0; q < 2; ++q) {
            const int li = q * 256 + tid;
            const unsigned short* gp = Bw + (size_t)(col0 + (li >> 2)) * K + k0 + (li & 3) * 8;
            __builtin_amdgcn_global_load_lds(
                (const __attribute__((address_space(1))) unsigned int*)gp,
                (__attribute__((address_space(3))) unsigned int*)&Bs[li * 8], 16, 0, 0);
        }
        __syncthreads();

        bf16x8 af[4], bfv[4];
        #pragma unroll
        for (int i = 0; i < 4; ++i) {
            af[i]  = *(const bf16x8*)&As[(m_off + i * 16 + lane_m) * 32 + lane_k];
            bfv[i] = *(const bf16x8*)&Bs[(n_off + i * 16 + lane_m) * 32 + lane_k];
        }
        #pragma unroll
        for (int i = 0; i < 4; ++i)
            #pragma unroll
            for (int j = 0; j < 4; ++j)
                acc[i][j] = __builtin_amdgcn_mfma_f32_16x16x32_bf16(af[i], bfv[j], acc[i][j], 0, 0, 0);
        __syncthreads();
    }

    // Epilogue. C/D layout: col = lane&15, row = (lane>>4)*4 + reg
    #pragma unroll
    for (int i = 0; i < 4; ++i) {
        #pragma unroll
        for (int r = 0; r < 4; ++r) {
            const int row = row0 + m_off + i * 16 + (lane >> 4) * 4 + r;
            if (row < M) {
                #pragma unroll
                for (int j = 0; j < 4; ++j) {
                    const int col = col0 + n_off + j * 16 + lane_m;
                    float v = acc[i][j][r] + bias[col];
                    if (GELU) v = gelu_tanh_f(v);
                    C[(size_t)row * N + col] = f2bf(v);
                }
            }
        }
    }
}

// ---------------------------------------------------------------------------
// Residual + LayerNorm (ddof=1): out = res + a*(x-mean)/(std+eps)+b
// res (proj bf16), x = f2 (bf16). One wave per row of 512.
// ---------------------------------------------------------------------------
__global__ __launch_bounds__(256) void ln_res_kernel(
    const unsigned short* __restrict__ f2, const unsigned short* __restrict__ res,
    float* __restrict__ out,
    const float* __restrict__ a, const float* __restrict__ b, int M)
{
    const int wave = threadIdx.x >> 6;
    const int lane = threadIdx.x & 63;
    const int row = blockIdx.x * 4 + wave;
    if (row >= M) return;
    const int d0 = lane * 8;

    ushort8 xu = *(const ushort8*)(f2  + (size_t)row * DD + d0);
    ushort8 ru = *(const ushort8*)(res + (size_t)row * DD + d0);
    float xs[8], rs[8];
    float s1 = 0.f, s2 = 0.f;
    #pragma unroll
    for (int i = 0; i < 8; ++i) {
        float v = bf2f(xu[i]);
        xs[i] = v; rs[i] = bf2f(ru[i]);
        s1 += v; s2 += v * v;
    }
    #pragma unroll
    for (int off = 32; off > 0; off >>= 1) {
        s1 += __shfl_xor(s1, off, 64);
        s2 += __shfl_xor(s2, off, 64);
    }
    const float mean = s1 * (1.f / 512.f);
    float var = (s2 - 512.f * mean * mean) * (1.f / 511.f);
    var = fmaxf(var, 0.f);
    const float rinv = 1.f / (sqrtf(var) + 1e-6f);

    float4 a0 = *(const float4*)(a + d0);
    float4 a1 = *(const float4*)(a + d0 + 4);
    float4 b0 = *(const float4*)(b + d0);
    float4 b1 = *(const float4*)(b + d0 + 4);
    float av[8] = {a0.x,a0.y,a0.z,a0.w,a1.x,a1.y,a1.z,a1.w};
    float bv[8] = {b0.x,b0.y,b0.z,b0.w,b1.x,b1.y,b1.z,b1.w};

    float4 o0, o1;
    float ov[8];
    #pragma unroll
    for (int i = 0; i < 8; ++i)
        ov[i] = rs[i] + av[i] * (xs[i] - mean) * rinv + bv[i];
    o0.x=ov[0]; o0.y=ov[1]; o0.z=ov[2]; o0.w=ov[3];
    o1.x=ov[4]; o1.y=ov[5]; o1.z=ov[6]; o1.w=ov[7];
    float* op = out + (size_t)row * DD + d0;
    *(float4*)op = o0;
    *(float4*)(op + 4) = o1;
}

// ---------------------------------------------------------------------------
extern "C" void kernel_launch(void* const* d_in, const int* in_sizes, int n_in,
                              void* d_out, int out_size, void* d_ws, size_t ws_size,
                              hipStream_t stream) {
    const float* img       = (const float*)d_in[0];
    const float* title     = (const float*)d_in[1];
    const int*   mask      = (const int*)  d_in[2];
    const float* scale_img = (const float*)d_in[3];
    const float* scale_tit = (const float*)d_in[4];
    const float* w_proj    = (const float*)d_in[5];
    const float* b_proj    = (const float*)d_in[6];
    const float* w1_img    = (const float*)d_in[7];
    const float* b1_img    = (const float*)d_in[8];
    const float* w2_img    = (const float*)d_in[9];
    const float* b2_img    = (const float*)d_in[10];
    const float* w1_tit    = (const float*)d_in[11];
    const float* b1_tit    = (const float*)d_in[12];
    const float* w2_tit    = (const float*)d_in[13];
    const float* b2_tit    = (const float*)d_in[14];
    const float* ln_a_img  = (const float*)d_in[15];
    const float* ln_b_img  = (const float*)d_in[16];
    const float* ln_a_tit  = (const float*)d_in[17];
    const float* ln_b_tit  = (const float*)d_in[18];

    float* out = (float*)d_out;
    unsigned short* hid_bf = (unsigned short*)d_ws;                       // R0 (early)
    unsigned short* act    = (unsigned short*)d_ws;                       // R0 (late)
    unsigned short* out_bf = (unsigned short*)((char*)d_ws + R1_OFF);     // R1
    unsigned short* f2b    = (unsigned short*)((char*)d_ws + R2_OFF);     // R2
    unsigned short* wp_bf  = (unsigned short*)((char*)d_ws + R3_OFF);     // R3
    unsigned short* w1i_bf = wp_bf  + 262144;
    unsigned short* w2i_bf = w1i_bf + 1048576;
    unsigned short* w1t_bf = w2i_bf + 1048576;
    unsigned short* w2t_bf = w1t_bf + 1048576;

    // 0) weights -> bf16
    cvt_kernel<<<(262144/4 + 255)/256, 256, 0, stream>>>(w_proj, wp_bf, 262144/4);
    cvt_kernel<<<(1048576/4 + 255)/256, 256, 0, stream>>>(w1_img, w1i_bf, 1048576/4);
    cvt_kernel<<<(1048576/4 + 255)/256, 256, 0, stream>>>(w2_img, w2i_bf, 1048576/4);
    cvt_kernel<<<(1048576/4 + 255)/256, 256, 0, stream>>>(w1_tit, w1t_bf, 1048576/4);
    cvt_kernel<<<(1048576/4 + 255)/256, 256, 0, stream>>>(w2_tit, w2t_bf, 1048576/4);

    // 1) MFMA attention -> hid_bf
    attn_kernel<<<BL * HH, 256, 0, stream>>>(img, title, mask, scale_img, scale_tit, hid_bf);

    // 2) proj over all 55200 rows -> out_bf (bf16 only)
    gemm_mfma<false><<<dim3(DD/128, (ROWS_A + 127)/128), 256, 0, stream>>>(
        hid_bf, wp_bf, b_proj, out_bf, ROWS_A, DD, DD);

    // 3) img branch (16000 rows)
    gemm_mfma<true><<<dim3(DFF/128, (ROWS_I + 127)/128), 256, 0, stream>>>(
        out_bf, w1i_bf, b1_img, act, ROWS_I, DFF, DD);
    gemm_mfma<false><<<dim3(DD/128, (ROWS_I + 127)/128), 256, 0, stream>>>(
        act, w2i_bf, b2_img, f2b, ROWS_I, DD, DFF);
    ln_res_kernel<<<(ROWS_I + 3)/4, 256, 0, stream>>>(f2b, out_bf, out, ln_a_img, ln_b_img, ROWS_I);

    // 4) tit branch (39200 rows, two chunks of 19600)
    for (int c = 0; c < 2; ++c) {
        const unsigned short* a1 = out_bf + (size_t)(ROWS_I + c * CHUNK) * DD;
        float* o1 = out + OUT_I_ELEMS + (size_t)c * CHUNK * DD;
        gemm_mfma<true><<<dim3(DFF/128, (CHUNK + 127)/128), 256, 0, stream>>>(
            a1, w1t_bf, b1_tit, act, CHUNK, DFF, DD);
        gemm_mfma<false><<<dim3(DD/128, (CHUNK + 127)/128), 256, 0, stream>>>(
            act, w2t_bf, b2_tit, f2b, CHUNK, DD, DFF);
        ln_res_kernel<<<(CHUNK + 3)/4, 256, 0, stream>>>(
            f2b, out_bf + (size_t)(ROWS_I + c * CHUNK) * DD, o1, ln_a_tit, ln_b_tit, CHUNK);
    }
}